// Round 2
// baseline (244.254 us; speedup 1.0000x reference)
//
#include <hip/hip_runtime.h>
#include <hip/hip_bf16.h>
#include <stdint.h>

// Problem: B=2, S=4096, D=512, H=8, hd=64. fp32 in/out, bf16 MFMA internally.
// Dispatches: cvt_all -> gemm_qkv -> flash -> gemm_out.
// R9: flash is LDS-throughput-bound (R8 post-mortem: 288 ds_read_b128/CU/tile
// ~= wall). Raise reuse: 64 q-rows per wave (qh 0..3), so each shared K/V
// ds_read_b128 feeds 4 MFMAs (was 1 in R8, 2 in v4). 128-thread blocks
// (2 waves), grid (32,16) = 2 blocks/CU, 1 wave/SIMD, VGPR-heavy by design.
// Non-flash kernels unchanged (R6).
//
// ws layout:
//   [0,   8MB)  Xb    bf16 [8192,512]
//   [8,  10MB)  Wqt/Wkt/Wvt/Wot bf16 [512,512] each ([n][k]; QKV contiguous)
//   [10, 18MB)  Qb    bf16 [B,H,S,64]  (pre-scaled by 0.125*log2e)
//   [18, 26MB)  Kb    bf16 [B,H,S,64]
//   [26, 34MB)  Vtb   bf16 [B,H,64,S]
//   [34, 42MB)  Atb   bf16 [B,S,512]

typedef __bf16 bf16x8 __attribute__((ext_vector_type(8)));
typedef float f32x4 __attribute__((ext_vector_type(4)));

using as1_void = __attribute__((address_space(1))) void;
using as3_void = __attribute__((address_space(3))) void;

__device__ __forceinline__ void gload16(const void* g, void* l) {
    __builtin_amdgcn_global_load_lds((const as1_void*)g, (as3_void*)l, 16, 0, 0);
}

__device__ __forceinline__ f32x4 mfma16(bf16x8 a, bf16x8 b, f32x4 c) {
    return __builtin_amdgcn_mfma_f32_16x16x32_bf16(a, b, c, 0, 0, 0);
}

__device__ __forceinline__ uint32_t pkbf(float a, float b) {
    union { __hip_bfloat16 h[2]; uint32_t u; } r;
    r.h[0] = __float2bfloat16(a);   // low 16 = even element
    r.h[1] = __float2bfloat16(b);
    return r.u;
}

// ---------------------------------------------------------------- converts (fused)
// blocks [0,1024): weight transposes (256 blocks per weight, 32x32 tiles)
// blocks [1024,5120): X fp32 -> bf16 cast (4 elems/thread)
__global__ void cvt_all(const float* __restrict__ X, __hip_bfloat16* __restrict__ Xb,
                        const float* __restrict__ w0, const float* __restrict__ w1,
                        const float* __restrict__ w2, const float* __restrict__ w3,
                        __hip_bfloat16* __restrict__ o0, __hip_bfloat16* __restrict__ o1,
                        __hip_bfloat16* __restrict__ o2, __hip_bfloat16* __restrict__ o3) {
    __shared__ float t[32][33];
    const int bid = blockIdx.x, tid = threadIdx.x;
    if (bid < 1024) {
        const float* W; __hip_bfloat16* O;
        switch (bid >> 8) {
            case 0: W = w0; O = o0; break;
            case 1: W = w1; O = o1; break;
            case 2: W = w2; O = o2; break;
            default: W = w3; O = o3; break;
        }
        int rem = bid & 255;
        int n0 = (rem & 15) * 32, k0 = (rem >> 4) * 32;
        int tx = tid & 31, ty = tid >> 5;
        for (int j = 0; j < 4; ++j)
            t[ty + 8 * j][tx] = W[(size_t)(k0 + ty + 8 * j) * 512 + n0 + tx];
        __syncthreads();
        for (int j = 0; j < 4; ++j)
            O[(size_t)(n0 + ty + 8 * j) * 512 + k0 + tx] = __float2bfloat16(t[tx][ty + 8 * j]);
    } else {
        int i = ((bid - 1024) * 256 + tid) * 4;   // covers exactly 8192*512
        float4 v = *reinterpret_cast<const float4*>(X + i);
        uint2 u;
        u.x = pkbf(v.x, v.y);
        u.y = pkbf(v.z, v.w);
        *reinterpret_cast<uint2*>(Xb + i) = u;
    }
}

// ---------------------------------------------------------------- fused QKV GEMM (R6)
__global__ __launch_bounds__(256, 2) void gemm_qkv(
    const __hip_bfloat16* __restrict__ A, const __hip_bfloat16* __restrict__ Bt,
    const float* __restrict__ bq, const float* __restrict__ bk, const float* __restrict__ bv,
    __hip_bfloat16* __restrict__ Qb, __hip_bfloat16* __restrict__ Kb,
    __hip_bfloat16* __restrict__ Vtb, float qs)
{
    const int K = 512;
    __shared__ __hip_bfloat16 Abuf[128 * 32];
    __shared__ __hip_bfloat16 Bbuf[128 * 32];
    const int tid = threadIdx.x, w = tid >> 6, lane = tid & 63;
    const int col = lane & 15, quad = lane >> 4;
    const int wr = w >> 1, wc = w & 1;
    const int tileN = blockIdx.x * 128, tileM = blockIdx.y * 128;

    f32x4 acc[4][4] = {};

    for (int k0 = 0; k0 < K; k0 += 32) {
        for (int i = 0; i < 2; ++i) {
            int g = w * 2 + i;
            int chunk = g * 64 + lane;
            int row = chunk >> 2, c8 = chunk & 3;
            gload16(A + (size_t)(tileM + row) * K + k0 + c8 * 8, Abuf + g * 512);
            gload16(Bt + (size_t)(tileN + row) * K + k0 + c8 * 8, Bbuf + g * 512);
        }
        __syncthreads();
        bf16x8 af[4], bfr[4];
        for (int mt = 0; mt < 4; ++mt)
            af[mt] = *reinterpret_cast<const bf16x8*>(Abuf + (wr * 64 + mt * 16 + col) * 32 + quad * 8);
        for (int nt = 0; nt < 4; ++nt)
            bfr[nt] = *reinterpret_cast<const bf16x8*>(Bbuf + (wc * 64 + nt * 16 + col) * 32 + quad * 8);
        for (int mt = 0; mt < 4; ++mt)
            for (int nt = 0; nt < 4; ++nt)
                acc[mt][nt] = mfma16(af[mt], bfr[nt], acc[mt][nt]);
        __syncthreads();
    }

    const int seg = (tileN + wc * 64) >> 9;   // wave-uniform
    const float* bias = (seg == 0) ? bq : (seg == 1) ? bk : bv;
    const float scale = (seg == 0) ? qs : 1.0f;
    __hip_bfloat16* outp = (seg == 0) ? Qb : (seg == 1) ? Kb : Vtb;

    for (int mt = 0; mt < 4; ++mt) {
        for (int nt = 0; nt < 4; ++nt) {
            int n = tileN + wc * 64 + nt * 16 + col;
            int nn = n & 511, h = nn >> 6, d = nn & 63;
            float bn = bias[nn];
            for (int r = 0; r < 4; ++r) {
                int m = tileM + wr * 64 + mt * 16 + quad * 4 + r;
                int b = m >> 12, s = m & 4095;
                float v = (acc[mt][nt][r] + bn) * scale;
                size_t off;
                if (seg < 2) off = (((size_t)(b * 8 + h) * 4096 + s) << 6) + d;
                else         off = (((size_t)(b * 8 + h) * 64 + d) << 12) + s;
                outp[off] = __float2bfloat16(v);
            }
        }
    }
}

// ---------------------------------------------------------------- final GEMM (Wo) (R6)
// 128(M) x 64(N) tiles -> 512 blocks = 2 blocks/CU.
__global__ __launch_bounds__(256, 2) void gemm_out(
    const __hip_bfloat16* __restrict__ A, const __hip_bfloat16* __restrict__ Bt,
    const float* __restrict__ bias, float* __restrict__ out)
{
    const int N = 512, K = 512;
    __shared__ __hip_bfloat16 Abuf[128 * 32];
    __shared__ __hip_bfloat16 Bbuf[64 * 32];
    const int tid = threadIdx.x, w = tid >> 6, lane = tid & 63;
    const int col = lane & 15, quad = lane >> 4;
    const int tileN = blockIdx.x * 64, tileM = blockIdx.y * 128;

    f32x4 acc[2][4] = {};

    for (int k0 = 0; k0 < K; k0 += 32) {
        for (int i = 0; i < 2; ++i) {
            int g = w * 2 + i;
            int chunk = g * 64 + lane;
            int row = chunk >> 2, c8 = chunk & 3;
            gload16(A + (size_t)(tileM + row) * K + k0 + c8 * 8, Abuf + g * 512);
        }
        {
            int row = tid >> 2, c8 = tid & 3;
            gload16(Bt + (size_t)(tileN + row) * K + k0 + c8 * 8, Bbuf + tid * 8);
        }
        __syncthreads();
        bf16x8 af[2], bfr[4];
        for (int mt = 0; mt < 2; ++mt)
            af[mt] = *reinterpret_cast<const bf16x8*>(Abuf + (w * 32 + mt * 16 + col) * 32 + quad * 8);
        for (int nt = 0; nt < 4; ++nt)
            bfr[nt] = *reinterpret_cast<const bf16x8*>(Bbuf + (nt * 16 + col) * 32 + quad * 8);
        for (int mt = 0; mt < 2; ++mt)
            for (int nt = 0; nt < 4; ++nt)
                acc[mt][nt] = mfma16(af[mt], bfr[nt], acc[mt][nt]);
        __syncthreads();
    }

    for (int mt = 0; mt < 2; ++mt) {
        for (int nt = 0; nt < 4; ++nt) {
            int n = tileN + nt * 16 + col;
            float bn = bias[n];
            for (int r = 0; r < 4; ++r) {
                int m = tileM + w * 32 + mt * 16 + quad * 4 + r;
                out[(size_t)m * N + n] = acc[mt][nt][r] + bn;
            }
        }
    }
}

// ---------------------------------------------------------------- flash attention (v6)
// v4 pipelined schedule, 64 q-rows per wave (qh 0..3). 2 waves/block (128 thr),
// grid (32,16) = 512 blocks = 2 blocks/CU = 1 wave/SIMD. Each shared K/V
// ds_read_b128 feeds 4 MFMAs -> per-CU LDS traffic ~halved vs v4, ~1/2.2 vs v5.
// LDS 48KB: KT 16K + VB 16K + TB 2x8K.
__global__ __launch_bounds__(128, 1) void flash(
    const __hip_bfloat16* __restrict__ Q,   // [B*H, 4096, 64] (pre-scaled)
    const __hip_bfloat16* __restrict__ Kq,  // [B*H, 4096, 64]
    const __hip_bfloat16* __restrict__ Vt,  // [B*H, 64, 4096]
    __hip_bfloat16* __restrict__ attnb)     // [B, 4096, 512]
{
    __shared__ __hip_bfloat16 KT[2][4096];  // 16 KB
    __shared__ __hip_bfloat16 VB[2][4096];  // 16 KB
    __shared__ uint32_t TB[2][2048];        // 16 KB, per-wave P^T staging (8KB/wave)

    const int bh = blockIdx.y, b = bh >> 3, h = bh & 7;
    const int tid = threadIdx.x, w = tid >> 6, lane = tid & 63;
    const int col = lane & 15, quad = lane >> 4;
    const int q0 = blockIdx.x * 128 + w * 64;
    const int c7 = col & 7;

    const __hip_bfloat16* Qh = Q + (size_t)bh * 4096 * 64;
    const __hip_bfloat16* Kh = Kq + (size_t)bh * 4096 * 64;
    const __hip_bfloat16* Vh = Vt + (size_t)bh * 64 * 4096;

    bf16x8 aq[4][2];
    for (int qh = 0; qh < 4; ++qh)
        for (int ks = 0; ks < 2; ++ks)
            aq[qh][ks] = *reinterpret_cast<const bf16x8*>(
                Qh + (size_t)(q0 + qh * 16 + col) * 64 + ks * 32 + quad * 8);

    // K/V tile staging: 128 threads x 4 x 16B = one 64x64 bf16 tile per buffer.
    // LDS dest wave-uniform base (HW adds lane*16); global source pre-swizzled
    // (^ row&7) so the swizzled ds_read below sees the right chunks.
    const __hip_bfloat16* ksrc[4];
    const __hip_bfloat16* vsrc[4];
    int ldsoff[4];
    for (int i = 0; i < 4; ++i) {
        int c = i * 128 + tid;
        int row = c >> 3, s8 = (c & 7) ^ (row & 7);
        ksrc[i] = Kh + row * 64 + s8 * 8;
        vsrc[i] = Vh + (size_t)row * 4096 + s8 * 8;
        ldsoff[i] = (i * 128 + w * 64) * 8;
    }

    bf16x8 ones;
    for (int j = 0; j < 8; ++j) ones[j] = (__bf16)1.0f;

    f32x4 o[4][4] = {};      // [dt][qh]
    f32x4 accl[4] = {};      // [qh]
    f32x4 sc[2][4][4];       // [buf][kg][qh]

    uint32_t* TBw = &TB[w][0];
    uint2* TBw2 = reinterpret_cast<uint2*>(TBw);

    for (int i = 0; i < 4; ++i) gload16(ksrc[i], &KT[0][ldsoff[i]]);
    for (int i = 0; i < 4; ++i) gload16(vsrc[i], &VB[0][ldsoff[i]]);
    for (int i = 0; i < 4; ++i) gload16(ksrc[i] + 4096, &KT[1][ldsoff[i]]);
    __syncthreads();

    for (int kg = 0; kg < 4; ++kg)
        for (int qh = 0; qh < 4; ++qh)
            sc[0][kg][qh] = (f32x4){0.f, 0.f, 0.f, 0.f};
    for (int ks = 0; ks < 2; ++ks)
        for (int kg = 0; kg < 4; ++kg) {
            bf16x8 ak = *reinterpret_cast<const bf16x8*>(
                &KT[0][(kg * 16 + col) * 64 + (((ks * 4 + quad) ^ c7) << 3)]);
            for (int qh = 0; qh < 4; ++qh)
                sc[0][kg][qh] = mfma16(ak, aq[qh][ks], sc[0][kg][qh]);
        }
    __syncthreads();

#define FLASH_BODY(KT_, P_)                                                     \
    {                                                                           \
        const int kt_ = (KT_);                                                  \
        int kk = kt_ + 2; if (kk > 63) kk = 63;                                 \
        for (int i = 0; i < 4; ++i)                                             \
            gload16(ksrc[i] + (size_t)kk * 4096, &KT[(P_)][ldsoff[i]]);         \
        for (int i = 0; i < 4; ++i)                                             \
            gload16(vsrc[i] + (size_t)(kt_ + 1) * 64, &VB[1 - (P_)][ldsoff[i]]);\
        for (int kg = 0; kg < 4; ++kg)                                          \
            for (int qh = 0; qh < 4; ++qh) {                                    \
                f32x4 v = sc[(P_)][kg][qh];                                     \
                uint2 u;                                                        \
                u.x = pkbf(__builtin_amdgcn_exp2f(v[0]),                        \
                           __builtin_amdgcn_exp2f(v[1]));                       \
                u.y = pkbf(__builtin_amdgcn_exp2f(v[2]),                        \
                           __builtin_amdgcn_exp2f(v[3]));                       \
                TBw2[(qh * 16 + col) * 16 +                                     \
                     (((kg * 2 + (quad >> 1)) ^ c7) << 1) + (quad & 1)] = u;    \
            }                                                                   \
        for (int kg = 0; kg < 4; ++kg)                                          \
            for (int qh = 0; qh < 4; ++qh)                                      \
                sc[1 - (P_)][kg][qh] = (f32x4){0.f, 0.f, 0.f, 0.f};             \
        for (int ks = 0; ks < 2; ++ks)                                          \
            for (int kg = 0; kg < 4; ++kg) {                                    \
                bf16x8 ak = *reinterpret_cast<const bf16x8*>(                   \
                    &KT[1 - (P_)][(kg * 16 + col) * 64 +                        \
                                  (((ks * 4 + quad) ^ c7) << 3)]);              \
                for (int qh = 0; qh < 4; ++qh)                                  \
                    sc[1 - (P_)][kg][qh] =                                      \
                        mfma16(ak, aq[qh][ks], sc[1 - (P_)][kg][qh]);           \
            }                                                                   \
        bf16x8 bp[4][2];                                                        \
        for (int qh = 0; qh < 4; ++qh)                                          \
            for (int ks = 0; ks < 2; ++ks)                                      \
                bp[qh][ks] = *reinterpret_cast<const bf16x8*>(                  \
                    &TBw[(qh * 16 + col) * 32 + (((ks * 4 + quad) ^ c7) << 2)]);\
        for (int ks = 0; ks < 2; ++ks) {                                        \
            for (int dt = 0; dt < 4; ++dt) {                                    \
                bf16x8 av = *reinterpret_cast<const bf16x8*>(                   \
                    &VB[(P_)][(dt * 16 + col) * 64 +                            \
                              (((ks * 4 + quad) ^ c7) << 3)]);                  \
                for (int qh = 0; qh < 4; ++qh)                                  \
                    o[dt][qh] = mfma16(av, bp[qh][ks], o[dt][qh]);              \
            }                                                                   \
            for (int qh = 0; qh < 4; ++qh)                                      \
                accl[qh] = mfma16(ones, bp[qh][ks], accl[qh]);                  \
        }                                                                       \
        __syncthreads();                                                        \
    }

    FLASH_BODY(0, 0)
    for (int kth = 0; kth < 31; ++kth) {
        FLASH_BODY(2 * kth + 1, 1)
        FLASH_BODY(2 * kth + 2, 0)
    }
    {
        for (int kg = 0; kg < 4; ++kg)
            for (int qh = 0; qh < 4; ++qh) {
                f32x4 v = sc[1][kg][qh];
                uint2 u;
                u.x = pkbf(__builtin_amdgcn_exp2f(v[0]), __builtin_amdgcn_exp2f(v[1]));
                u.y = pkbf(__builtin_amdgcn_exp2f(v[2]), __builtin_amdgcn_exp2f(v[3]));
                TBw2[(qh * 16 + col) * 16 + (((kg * 2 + (quad >> 1)) ^ c7) << 1) + (quad & 1)] = u;
            }
        bf16x8 bp[4][2];
        for (int qh = 0; qh < 4; ++qh)
            for (int ks = 0; ks < 2; ++ks)
                bp[qh][ks] = *reinterpret_cast<const bf16x8*>(
                    &TBw[(qh * 16 + col) * 32 + (((ks * 4 + quad) ^ c7) << 2)]);
        for (int ks = 0; ks < 2; ++ks) {
            for (int dt = 0; dt < 4; ++dt) {
                bf16x8 av = *reinterpret_cast<const bf16x8*>(
                    &VB[1][(dt * 16 + col) * 64 + (((ks * 4 + quad) ^ c7) << 3)]);
                for (int qh = 0; qh < 4; ++qh)
                    o[dt][qh] = mfma16(av, bp[qh][ks], o[dt][qh]);
            }
            for (int qh = 0; qh < 4; ++qh)
                accl[qh] = mfma16(ones, bp[qh][ks], accl[qh]);
        }
    }
#undef FLASH_BODY

    for (int qh = 0; qh < 4; ++qh) {
        float inv = 1.0f / accl[qh][0];
        int s = q0 + qh * 16 + col;
        __hip_bfloat16* dst = attnb + ((size_t)b * 4096 + s) * 512 + h * 64 + quad * 4;
        for (int dt = 0; dt < 4; ++dt) {
            uint2 u;
            u.x = pkbf(o[dt][qh][0] * inv, o[dt][qh][1] * inv);
            u.y = pkbf(o[dt][qh][2] * inv, o[dt][qh][3] * inv);
            *reinterpret_cast<uint2*>(dst + dt * 16) = u;
        }
    }
}

// ---------------------------------------------------------------- launch
extern "C" void kernel_launch(void* const* d_in, const int* in_sizes, int n_in,
                              void* d_out, int out_size, void* d_ws, size_t ws_size,
                              hipStream_t stream) {
    const float* X  = (const float*)d_in[0];
    const float* Wq = (const float*)d_in[1];
    const float* bq = (const float*)d_in[2];
    const float* Wk = (const float*)d_in[3];
    const float* bk = (const float*)d_in[4];
    const float* Wv = (const float*)d_in[5];
    const float* bv = (const float*)d_in[6];
    const float* Wo = (const float*)d_in[7];
    const float* bo = (const float*)d_in[8];
    float* out = (float*)d_out;

    char* ws = (char*)d_ws;
    __hip_bfloat16* Xb  = (__hip_bfloat16*)(ws);
    __hip_bfloat16* Wqt = (__hip_bfloat16*)(ws + ((size_t)8 << 20));
    __hip_bfloat16* Wkt = Wqt + 512 * 512;
    __hip_bfloat16* Wvt = Wkt + 512 * 512;
    __hip_bfloat16* Wot = Wvt + 512 * 512;
    __hip_bfloat16* Qb  = (__hip_bfloat16*)(ws + ((size_t)10 << 20));
    __hip_bfloat16* Kb  = (__hip_bfloat16*)(ws + ((size_t)18 << 20));
    __hip_bfloat16* Vtb = (__hip_bfloat16*)(ws + ((size_t)26 << 20));
    __hip_bfloat16* Atb = (__hip_bfloat16*)(ws + ((size_t)34 << 20));

    cvt_all<<<5120, 256, 0, stream>>>(X, Xb, Wq, Wk, Wv, Wo, Wqt, Wkt, Wvt, Wot);

    const float qs = 0.125f * 1.4426950408889634f;  // (1/sqrt(64)) * log2(e)
    gemm_qkv<<<dim3(12, 64), 256, 0, stream>>>(Xb, Wqt, bq, bk, bv, Qb, Kb, Vtb, qs);
    flash<<<dim3(32, 16), 128, 0, stream>>>(Qb, Kb, Vtb, Atb);
    gemm_out<<<dim3(8, 64), 256, 0, stream>>>(Atb, Wot, bo, out);
}

// Round 3
// 213.229 us; speedup vs baseline: 1.1455x; 1.1455x over previous
//
#include <hip/hip_runtime.h>
#include <hip/hip_bf16.h>
#include <stdint.h>

// Problem: B=2, S=4096, D=512, H=8, hd=64. fp32 in/out, bf16 MFMA internally.
// Dispatches: cvt_all -> gemm_qkv -> flash -> gemm_out.
// R10 (v7): revert flash to v4 shape (4 waves x 32 q-rows, 256 thr, 2 blk/CU,
// 2 waves/SIMD — measured best 103us). New mechanism: triple-buffered K/V with
// counted-vmcnt barriers (asm "s_waitcnt vmcnt(4); s_barrier") so each body's
// 4 global_load_lds stay in flight across the barrier (prefetch distance:
// K +3 tiles, V +2 tiles). Removes the per-body vmcnt(0) drain that
// __syncthreads forced. Plus s_setprio(1) around MFMA clusters (T5).
// LDS 64KB/block: KT 3x8K + VB 3x8K + TB 16K. Non-flash kernels unchanged.
//
// ws layout:
//   [0,   8MB)  Xb    bf16 [8192,512]
//   [8,  10MB)  Wqt/Wkt/Wvt/Wot bf16 [512,512] each ([n][k]; QKV contiguous)
//   [10, 18MB)  Qb    bf16 [B,H,S,64]  (pre-scaled by 0.125*log2e)
//   [18, 26MB)  Kb    bf16 [B,H,S,64]
//   [26, 34MB)  Vtb   bf16 [B,H,64,S]
//   [34, 42MB)  Atb   bf16 [B,S,512]

typedef __bf16 bf16x8 __attribute__((ext_vector_type(8)));
typedef float f32x4 __attribute__((ext_vector_type(4)));

using as1_void = __attribute__((address_space(1))) void;
using as3_void = __attribute__((address_space(3))) void;

__device__ __forceinline__ void gload16(const void* g, void* l) {
    __builtin_amdgcn_global_load_lds((const as1_void*)g, (as3_void*)l, 16, 0, 0);
}

__device__ __forceinline__ f32x4 mfma16(bf16x8 a, bf16x8 b, f32x4 c) {
    return __builtin_amdgcn_mfma_f32_16x16x32_bf16(a, b, c, 0, 0, 0);
}

__device__ __forceinline__ uint32_t pkbf(float a, float b) {
    union { __hip_bfloat16 h[2]; uint32_t u; } r;
    r.h[0] = __float2bfloat16(a);   // low 16 = even element
    r.h[1] = __float2bfloat16(b);
    return r.u;
}

// ---------------------------------------------------------------- converts (fused)
// blocks [0,1024): weight transposes (256 blocks per weight, 32x32 tiles)
// blocks [1024,5120): X fp32 -> bf16 cast (4 elems/thread)
__global__ void cvt_all(const float* __restrict__ X, __hip_bfloat16* __restrict__ Xb,
                        const float* __restrict__ w0, const float* __restrict__ w1,
                        const float* __restrict__ w2, const float* __restrict__ w3,
                        __hip_bfloat16* __restrict__ o0, __hip_bfloat16* __restrict__ o1,
                        __hip_bfloat16* __restrict__ o2, __hip_bfloat16* __restrict__ o3) {
    __shared__ float t[32][33];
    const int bid = blockIdx.x, tid = threadIdx.x;
    if (bid < 1024) {
        const float* W; __hip_bfloat16* O;
        switch (bid >> 8) {
            case 0: W = w0; O = o0; break;
            case 1: W = w1; O = o1; break;
            case 2: W = w2; O = o2; break;
            default: W = w3; O = o3; break;
        }
        int rem = bid & 255;
        int n0 = (rem & 15) * 32, k0 = (rem >> 4) * 32;
        int tx = tid & 31, ty = tid >> 5;
        for (int j = 0; j < 4; ++j)
            t[ty + 8 * j][tx] = W[(size_t)(k0 + ty + 8 * j) * 512 + n0 + tx];
        __syncthreads();
        for (int j = 0; j < 4; ++j)
            O[(size_t)(n0 + ty + 8 * j) * 512 + k0 + tx] = __float2bfloat16(t[tx][ty + 8 * j]);
    } else {
        int i = ((bid - 1024) * 256 + tid) * 4;   // covers exactly 8192*512
        float4 v = *reinterpret_cast<const float4*>(X + i);
        uint2 u;
        u.x = pkbf(v.x, v.y);
        u.y = pkbf(v.z, v.w);
        *reinterpret_cast<uint2*>(Xb + i) = u;
    }
}

// ---------------------------------------------------------------- fused QKV GEMM (R6)
__global__ __launch_bounds__(256, 2) void gemm_qkv(
    const __hip_bfloat16* __restrict__ A, const __hip_bfloat16* __restrict__ Bt,
    const float* __restrict__ bq, const float* __restrict__ bk, const float* __restrict__ bv,
    __hip_bfloat16* __restrict__ Qb, __hip_bfloat16* __restrict__ Kb,
    __hip_bfloat16* __restrict__ Vtb, float qs)
{
    const int K = 512;
    __shared__ __hip_bfloat16 Abuf[128 * 32];
    __shared__ __hip_bfloat16 Bbuf[128 * 32];
    const int tid = threadIdx.x, w = tid >> 6, lane = tid & 63;
    const int col = lane & 15, quad = lane >> 4;
    const int wr = w >> 1, wc = w & 1;
    const int tileN = blockIdx.x * 128, tileM = blockIdx.y * 128;

    f32x4 acc[4][4] = {};

    for (int k0 = 0; k0 < K; k0 += 32) {
        for (int i = 0; i < 2; ++i) {
            int g = w * 2 + i;
            int chunk = g * 64 + lane;
            int row = chunk >> 2, c8 = chunk & 3;
            gload16(A + (size_t)(tileM + row) * K + k0 + c8 * 8, Abuf + g * 512);
            gload16(Bt + (size_t)(tileN + row) * K + k0 + c8 * 8, Bbuf + g * 512);
        }
        __syncthreads();
        bf16x8 af[4], bfr[4];
        for (int mt = 0; mt < 4; ++mt)
            af[mt] = *reinterpret_cast<const bf16x8*>(Abuf + (wr * 64 + mt * 16 + col) * 32 + quad * 8);
        for (int nt = 0; nt < 4; ++nt)
            bfr[nt] = *reinterpret_cast<const bf16x8*>(Bbuf + (wc * 64 + nt * 16 + col) * 32 + quad * 8);
        for (int mt = 0; mt < 4; ++mt)
            for (int nt = 0; nt < 4; ++nt)
                acc[mt][nt] = mfma16(af[mt], bfr[nt], acc[mt][nt]);
        __syncthreads();
    }

    const int seg = (tileN + wc * 64) >> 9;   // wave-uniform
    const float* bias = (seg == 0) ? bq : (seg == 1) ? bk : bv;
    const float scale = (seg == 0) ? qs : 1.0f;
    __hip_bfloat16* outp = (seg == 0) ? Qb : (seg == 1) ? Kb : Vtb;

    for (int mt = 0; mt < 4; ++mt) {
        for (int nt = 0; nt < 4; ++nt) {
            int n = tileN + wc * 64 + nt * 16 + col;
            int nn = n & 511, h = nn >> 6, d = nn & 63;
            float bn = bias[nn];
            for (int r = 0; r < 4; ++r) {
                int m = tileM + wr * 64 + mt * 16 + quad * 4 + r;
                int b = m >> 12, s = m & 4095;
                float v = (acc[mt][nt][r] + bn) * scale;
                size_t off;
                if (seg < 2) off = (((size_t)(b * 8 + h) * 4096 + s) << 6) + d;
                else         off = (((size_t)(b * 8 + h) * 64 + d) << 12) + s;
                outp[off] = __float2bfloat16(v);
            }
        }
    }
}

// ---------------------------------------------------------------- final GEMM (Wo) (R6)
// 128(M) x 64(N) tiles -> 512 blocks = 2 blocks/CU.
__global__ __launch_bounds__(256, 2) void gemm_out(
    const __hip_bfloat16* __restrict__ A, const __hip_bfloat16* __restrict__ Bt,
    const float* __restrict__ bias, float* __restrict__ out)
{
    const int N = 512, K = 512;
    __shared__ __hip_bfloat16 Abuf[128 * 32];
    __shared__ __hip_bfloat16 Bbuf[64 * 32];
    const int tid = threadIdx.x, w = tid >> 6, lane = tid & 63;
    const int col = lane & 15, quad = lane >> 4;
    const int tileN = blockIdx.x * 64, tileM = blockIdx.y * 128;

    f32x4 acc[2][4] = {};

    for (int k0 = 0; k0 < K; k0 += 32) {
        for (int i = 0; i < 2; ++i) {
            int g = w * 2 + i;
            int chunk = g * 64 + lane;
            int row = chunk >> 2, c8 = chunk & 3;
            gload16(A + (size_t)(tileM + row) * K + k0 + c8 * 8, Abuf + g * 512);
        }
        {
            int row = tid >> 2, c8 = tid & 3;
            gload16(Bt + (size_t)(tileN + row) * K + k0 + c8 * 8, Bbuf + tid * 8);
        }
        __syncthreads();
        bf16x8 af[2], bfr[4];
        for (int mt = 0; mt < 2; ++mt)
            af[mt] = *reinterpret_cast<const bf16x8*>(Abuf + (w * 32 + mt * 16 + col) * 32 + quad * 8);
        for (int nt = 0; nt < 4; ++nt)
            bfr[nt] = *reinterpret_cast<const bf16x8*>(Bbuf + (nt * 16 + col) * 32 + quad * 8);
        for (int mt = 0; mt < 2; ++mt)
            for (int nt = 0; nt < 4; ++nt)
                acc[mt][nt] = mfma16(af[mt], bfr[nt], acc[mt][nt]);
        __syncthreads();
    }

    for (int mt = 0; mt < 2; ++mt) {
        for (int nt = 0; nt < 4; ++nt) {
            int n = tileN + nt * 16 + col;
            float bn = bias[n];
            for (int r = 0; r < 4; ++r) {
                int m = tileM + w * 32 + mt * 16 + quad * 4 + r;
                out[(size_t)m * N + n] = acc[mt][nt][r] + bn;
            }
        }
    }
}

// ---------------------------------------------------------------- flash attention (v7)
// v4 shape (4 waves x 32 q-rows, 256 thr, 2 blocks/CU) + triple-buffered K/V
// with counted-vmcnt barriers. Loads issued in body t are consumed in body
// t+2 (K prefetch +3 tiles, V +2), so "s_waitcnt vmcnt(4); s_barrier" leaves
// the current body's 4 loads in flight. Buffer rotation mod 3:
//   body t: write K(t+3)->KT[t%3], V(t+2)->VB[(t+2)%3];
//           QK reads KT[(t+1)%3], PV reads VB[t%3]; sc parity t&1.
// LDS 64KB: KT 3x8K + VB 3x8K + TB 4x4K.
__global__ __launch_bounds__(256) void flash(
    const __hip_bfloat16* __restrict__ Q,   // [B*H, 4096, 64] (pre-scaled)
    const __hip_bfloat16* __restrict__ Kq,  // [B*H, 4096, 64]
    const __hip_bfloat16* __restrict__ Vt,  // [B*H, 64, 4096]
    __hip_bfloat16* __restrict__ attnb)     // [B, 4096, 512]
{
    __shared__ __hip_bfloat16 KT[3][4096];  // 24 KB
    __shared__ __hip_bfloat16 VB[3][4096];  // 24 KB
    __shared__ uint32_t TB[4][1024];        // 16 KB, per-wave P^T staging

    const int bh = blockIdx.y, b = bh >> 3, h = bh & 7;
    const int tid = threadIdx.x, w = tid >> 6, lane = tid & 63;
    const int col = lane & 15, quad = lane >> 4;
    const int q0 = blockIdx.x * 128 + w * 32;
    const int c7 = col & 7;

    const __hip_bfloat16* Qh = Q + (size_t)bh * 4096 * 64;
    const __hip_bfloat16* Kh = Kq + (size_t)bh * 4096 * 64;
    const __hip_bfloat16* Vh = Vt + (size_t)bh * 64 * 4096;

    bf16x8 aq[2][2];
    for (int qh = 0; qh < 2; ++qh)
        for (int ks = 0; ks < 2; ++ks)
            aq[qh][ks] = *reinterpret_cast<const bf16x8*>(
                Qh + (size_t)(q0 + qh * 16 + col) * 64 + ks * 32 + quad * 8);

    const __hip_bfloat16* ksrc[2];
    const __hip_bfloat16* vsrc[2];
    int ldsoff[2];
    for (int i = 0; i < 2; ++i) {
        int c = i * 256 + tid;
        int row = c >> 3, s8 = (c & 7) ^ (row & 7);
        ksrc[i] = Kh + row * 64 + s8 * 8;
        vsrc[i] = Vh + (size_t)row * 4096 + s8 * 8;
        ldsoff[i] = (i * 256 + w * 64) * 8;
    }

    bf16x8 ones;
    for (int j = 0; j < 8; ++j) ones[j] = (__bf16)1.0f;

    f32x4 o[4][2] = {};
    f32x4 accl[2] = {};
    f32x4 sc[2][4][2];

    uint32_t* TBw = &TB[w][0];
    uint2* TBw2 = reinterpret_cast<uint2*>(TBw);

    // Prologue: K0,V0,K1,V1,K2 (10 VMEM insts/wave, issue order matters for
    // the counted waits below).
    gload16(ksrc[0], &KT[0][ldsoff[0]]);
    gload16(ksrc[1], &KT[0][ldsoff[1]]);
    gload16(vsrc[0], &VB[0][ldsoff[0]]);
    gload16(vsrc[1], &VB[0][ldsoff[1]]);
    gload16(ksrc[0] + 4096, &KT[1][ldsoff[0]]);
    gload16(ksrc[1] + 4096, &KT[1][ldsoff[1]]);
    gload16(vsrc[0] + 64, &VB[1][ldsoff[0]]);
    gload16(vsrc[1] + 64, &VB[1][ldsoff[1]]);
    gload16(ksrc[0] + 2 * 4096, &KT[2][ldsoff[0]]);
    gload16(ksrc[1] + 2 * 4096, &KT[2][ldsoff[1]]);
    // wait K0 (oldest 2 of 10) then publish
    asm volatile("s_waitcnt vmcnt(8)\n\ts_barrier" ::: "memory");

    for (int kg = 0; kg < 4; ++kg)
        for (int qh = 0; qh < 2; ++qh)
            sc[0][kg][qh] = (f32x4){0.f, 0.f, 0.f, 0.f};
    for (int ks = 0; ks < 2; ++ks)
        for (int kg = 0; kg < 4; ++kg) {
            bf16x8 ak = *reinterpret_cast<const bf16x8*>(
                &KT[0][(kg * 16 + col) * 64 + (((ks * 4 + quad) ^ c7) << 3)]);
            for (int qh = 0; qh < 2; ++qh)
                sc[0][kg][qh] = mfma16(ak, aq[qh][ks], sc[0][kg][qh]);
        }
    // wait V0,K1 done (leave V1,K2 = 4 in flight) then publish
    asm volatile("s_waitcnt vmcnt(4)\n\ts_barrier" ::: "memory");

// Body T_: consumes sc[SP] (tile T_), fills sc[1-SP] (tile T_+1 scores from
// KT[KR]), PV on VB[VR] (tile T_), prefetch K(T_+3)->KT[KW], V(T_+2)->VB[VW].
#define FLASH_BODY(T_, SP, KW, KR, VW, VR)                                      \
    {                                                                           \
        const int kt_ = (T_);                                                   \
        int kk = kt_ + 3; if (kk > 63) kk = 63;                                 \
        int vv = kt_ + 2; if (vv > 63) vv = 63;                                 \
        gload16(ksrc[0] + (size_t)kk * 4096, &KT[KW][ldsoff[0]]);               \
        gload16(ksrc[1] + (size_t)kk * 4096, &KT[KW][ldsoff[1]]);               \
        gload16(vsrc[0] + (size_t)vv * 64, &VB[VW][ldsoff[0]]);                 \
        gload16(vsrc[1] + (size_t)vv * 64, &VB[VW][ldsoff[1]]);                 \
        for (int kg = 0; kg < 4; ++kg)                                          \
            for (int qh = 0; qh < 2; ++qh) {                                    \
                f32x4 v = sc[SP][kg][qh];                                       \
                uint2 u;                                                        \
                u.x = pkbf(__builtin_amdgcn_exp2f(v[0]),                        \
                           __builtin_amdgcn_exp2f(v[1]));                       \
                u.y = pkbf(__builtin_amdgcn_exp2f(v[2]),                        \
                           __builtin_amdgcn_exp2f(v[3]));                       \
                TBw2[(qh * 16 + col) * 16 +                                     \
                     (((kg * 2 + (quad >> 1)) ^ c7) << 1) + (quad & 1)] = u;    \
            }                                                                   \
        for (int kg = 0; kg < 4; ++kg)                                          \
            for (int qh = 0; qh < 2; ++qh)                                      \
                sc[1 - (SP)][kg][qh] = (f32x4){0.f, 0.f, 0.f, 0.f};             \
        __builtin_amdgcn_s_setprio(1);                                          \
        for (int ks = 0; ks < 2; ++ks)                                          \
            for (int kg = 0; kg < 4; ++kg) {                                    \
                bf16x8 ak = *reinterpret_cast<const bf16x8*>(                   \
                    &KT[KR][(kg * 16 + col) * 64 +                              \
                            (((ks * 4 + quad) ^ c7) << 3)]);                    \
                for (int qh = 0; qh < 2; ++qh)                                  \
                    sc[1 - (SP)][kg][qh] =                                      \
                        mfma16(ak, aq[qh][ks], sc[1 - (SP)][kg][qh]);           \
            }                                                                   \
        __builtin_amdgcn_s_setprio(0);                                          \
        bf16x8 bp[2][2];                                                        \
        for (int qh = 0; qh < 2; ++qh)                                          \
            for (int ks = 0; ks < 2; ++ks)                                      \
                bp[qh][ks] = *reinterpret_cast<const bf16x8*>(                  \
                    &TBw[(qh * 16 + col) * 32 + (((ks * 4 + quad) ^ c7) << 2)]);\
        __builtin_amdgcn_s_setprio(1);                                          \
        for (int ks = 0; ks < 2; ++ks) {                                        \
            for (int dt = 0; dt < 4; ++dt) {                                    \
                bf16x8 av = *reinterpret_cast<const bf16x8*>(                   \
                    &VB[VR][(dt * 16 + col) * 64 +                              \
                            (((ks * 4 + quad) ^ c7) << 3)]);                    \
                for (int qh = 0; qh < 2; ++qh)                                  \
                    o[dt][qh] = mfma16(av, bp[qh][ks], o[dt][qh]);              \
            }                                                                   \
            accl[0] = mfma16(ones, bp[0][ks], accl[0]);                         \
            accl[1] = mfma16(ones, bp[1][ks], accl[1]);                         \
        }                                                                       \
        __builtin_amdgcn_s_setprio(0);                                          \
        asm volatile("s_waitcnt vmcnt(4)\n\ts_barrier" ::: "memory");           \
    }

    // bodies 0..59: period-6 schedule (sc parity x mod-3 buffers)
    for (int t6 = 0; t6 < 60; t6 += 6) {
        FLASH_BODY(t6 + 0, 0, 0, 1, 2, 0)
        FLASH_BODY(t6 + 1, 1, 1, 2, 0, 1)
        FLASH_BODY(t6 + 2, 0, 2, 0, 1, 2)
        FLASH_BODY(t6 + 3, 1, 0, 1, 2, 0)
        FLASH_BODY(t6 + 4, 0, 1, 2, 0, 1)
        FLASH_BODY(t6 + 5, 1, 2, 0, 1, 2)
    }
    FLASH_BODY(60, 0, 0, 1, 2, 0)
    FLASH_BODY(61, 1, 1, 2, 0, 1)
    FLASH_BODY(62, 0, 2, 0, 1, 2)
#undef FLASH_BODY

    // tail: tile 63 — softmax sc[1], PV from VB[0] (V63, loaded body 61)
    {
        for (int kg = 0; kg < 4; ++kg)
            for (int qh = 0; qh < 2; ++qh) {
                f32x4 v = sc[1][kg][qh];
                uint2 u;
                u.x = pkbf(__builtin_amdgcn_exp2f(v[0]), __builtin_amdgcn_exp2f(v[1]));
                u.y = pkbf(__builtin_amdgcn_exp2f(v[2]), __builtin_amdgcn_exp2f(v[3]));
                TBw2[(qh * 16 + col) * 16 + (((kg * 2 + (quad >> 1)) ^ c7) << 1) + (quad & 1)] = u;
            }
        bf16x8 bp[2][2];
        for (int qh = 0; qh < 2; ++qh)
            for (int ks = 0; ks < 2; ++ks)
                bp[qh][ks] = *reinterpret_cast<const bf16x8*>(
                    &TBw[(qh * 16 + col) * 32 + (((ks * 4 + quad) ^ c7) << 2)]);
        for (int ks = 0; ks < 2; ++ks) {
            for (int dt = 0; dt < 4; ++dt) {
                bf16x8 av = *reinterpret_cast<const bf16x8*>(
                    &VB[0][(dt * 16 + col) * 64 + (((ks * 4 + quad) ^ c7) << 3)]);
                for (int qh = 0; qh < 2; ++qh)
                    o[dt][qh] = mfma16(av, bp[qh][ks], o[dt][qh]);
            }
            accl[0] = mfma16(ones, bp[0][ks], accl[0]);
            accl[1] = mfma16(ones, bp[1][ks], accl[1]);
        }
    }

    for (int qh = 0; qh < 2; ++qh) {
        float inv = 1.0f / accl[qh][0];
        int s = q0 + qh * 16 + col;
        __hip_bfloat16* dst = attnb + ((size_t)b * 4096 + s) * 512 + h * 64 + quad * 4;
        for (int dt = 0; dt < 4; ++dt) {
            uint2 u;
            u.x = pkbf(o[dt][qh][0] * inv, o[dt][qh][1] * inv);
            u.y = pkbf(o[dt][qh][2] * inv, o[dt][qh][3] * inv);
            *reinterpret_cast<uint2*>(dst + dt * 16) = u;
        }
    }
}

// ---------------------------------------------------------------- launch
extern "C" void kernel_launch(void* const* d_in, const int* in_sizes, int n_in,
                              void* d_out, int out_size, void* d_ws, size_t ws_size,
                              hipStream_t stream) {
    const float* X  = (const float*)d_in[0];
    const float* Wq = (const float*)d_in[1];
    const float* bq = (const float*)d_in[2];
    const float* Wk = (const float*)d_in[3];
    const float* bk = (const float*)d_in[4];
    const float* Wv = (const float*)d_in[5];
    const float* bv = (const float*)d_in[6];
    const float* Wo = (const float*)d_in[7];
    const float* bo = (const float*)d_in[8];
    float* out = (float*)d_out;

    char* ws = (char*)d_ws;
    __hip_bfloat16* Xb  = (__hip_bfloat16*)(ws);
    __hip_bfloat16* Wqt = (__hip_bfloat16*)(ws + ((size_t)8 << 20));
    __hip_bfloat16* Wkt = Wqt + 512 * 512;
    __hip_bfloat16* Wvt = Wkt + 512 * 512;
    __hip_bfloat16* Wot = Wvt + 512 * 512;
    __hip_bfloat16* Qb  = (__hip_bfloat16*)(ws + ((size_t)10 << 20));
    __hip_bfloat16* Kb  = (__hip_bfloat16*)(ws + ((size_t)18 << 20));
    __hip_bfloat16* Vtb = (__hip_bfloat16*)(ws + ((size_t)26 << 20));
    __hip_bfloat16* Atb = (__hip_bfloat16*)(ws + ((size_t)34 << 20));

    cvt_all<<<5120, 256, 0, stream>>>(X, Xb, Wq, Wk, Wv, Wo, Wqt, Wkt, Wvt, Wot);

    const float qs = 0.125f * 1.4426950408889634f;  // (1/sqrt(64)) * log2(e)
    gemm_qkv<<<dim3(12, 64), 256, 0, stream>>>(Xb, Wqt, bq, bk, bv, Qb, Kb, Vtb, qs);
    flash<<<dim3(32, 16), 256, 0, stream>>>(Qb, Kb, Vtb, Atb);
    gemm_out<<<dim3(8, 64), 256, 0, stream>>>(Atb, Wot, bo, out);
}

// Round 5
// 209.577 us; speedup vs baseline: 1.1655x; 1.0174x over previous
//
#include <hip/hip_runtime.h>
#include <hip/hip_bf16.h>
#include <stdint.h>

// Problem: B=2, S=4096, D=512, H=8, hd=64. fp32 in/out, bf16 MFMA internally.
// Dispatches: cvt_all -> gemm_qkv -> flash -> gemm_out.
// R12 (v8b): identical to R11/v8 (32x32x16 MFMA flash, in-register softmax
// exchange via permlane32_swap, no TB LDS) except the lane exchange now uses
// __builtin_amdgcn_permlane32_swap (inline-asm fallback) — the only construct
// that could have broken the failed R11 run. Non-flash kernels unchanged (R6).
//
// ws layout:
//   [0,   8MB)  Xb    bf16 [8192,512]
//   [8,  10MB)  Wqt/Wkt/Wvt/Wot bf16 [512,512] each ([n][k]; QKV contiguous)
//   [10, 18MB)  Qb    bf16 [B,H,S,64]  (pre-scaled by 0.125*log2e)
//   [18, 26MB)  Kb    bf16 [B,H,S,64]
//   [26, 34MB)  Vtb   bf16 [B,H,64,S]
//   [34, 42MB)  Atb   bf16 [B,S,512]

typedef __bf16 bf16x8 __attribute__((ext_vector_type(8)));
typedef float f32x4 __attribute__((ext_vector_type(4)));
typedef float f32x16 __attribute__((ext_vector_type(16)));

using as1_void = __attribute__((address_space(1))) void;
using as3_void = __attribute__((address_space(3))) void;

__device__ __forceinline__ void gload16(const void* g, void* l) {
    __builtin_amdgcn_global_load_lds((const as1_void*)g, (as3_void*)l, 16, 0, 0);
}

__device__ __forceinline__ f32x4 mfma16(bf16x8 a, bf16x8 b, f32x4 c) {
    return __builtin_amdgcn_mfma_f32_16x16x32_bf16(a, b, c, 0, 0, 0);
}

__device__ __forceinline__ f32x16 mfma32(bf16x8 a, bf16x8 b, f32x16 c) {
    return __builtin_amdgcn_mfma_f32_32x32x16_bf16(a, b, c, 0, 0, 0);
}

__device__ __forceinline__ uint32_t pkbf(float a, float b) {
    union { __hip_bfloat16 h[2]; uint32_t u; } r;
    r.h[0] = __float2bfloat16(a);   // low 16 = even element
    r.h[1] = __float2bfloat16(b);
    return r.u;
}

// Exchange: a's hi-32-lane values <-> b's lo-32-lane values.
// After: lane<32 keeps own a, gets partner's (lane+32) a into b;
//        lane>=32 keeps own b, gets partner's (lane-32) b into a.
__device__ __forceinline__ void pl32swap(uint32_t& a, uint32_t& b) {
#if __has_builtin(__builtin_amdgcn_permlane32_swap)
    typedef unsigned int uint32x2_t __attribute__((ext_vector_type(2)));
    uint32x2_t r = __builtin_amdgcn_permlane32_swap(a, b, false, false);
    a = r[0];
    b = r[1];
#else
    asm volatile("v_permlane32_swap_b32 %0, %1" : "+v"(a), "+v"(b));
#endif
}

// ---------------------------------------------------------------- converts (fused)
// blocks [0,1024): weight transposes (256 blocks per weight, 32x32 tiles)
// blocks [1024,5120): X fp32 -> bf16 cast (4 elems/thread)
__global__ void cvt_all(const float* __restrict__ X, __hip_bfloat16* __restrict__ Xb,
                        const float* __restrict__ w0, const float* __restrict__ w1,
                        const float* __restrict__ w2, const float* __restrict__ w3,
                        __hip_bfloat16* __restrict__ o0, __hip_bfloat16* __restrict__ o1,
                        __hip_bfloat16* __restrict__ o2, __hip_bfloat16* __restrict__ o3) {
    __shared__ float t[32][33];
    const int bid = blockIdx.x, tid = threadIdx.x;
    if (bid < 1024) {
        const float* W; __hip_bfloat16* O;
        switch (bid >> 8) {
            case 0: W = w0; O = o0; break;
            case 1: W = w1; O = o1; break;
            case 2: W = w2; O = o2; break;
            default: W = w3; O = o3; break;
        }
        int rem = bid & 255;
        int n0 = (rem & 15) * 32, k0 = (rem >> 4) * 32;
        int tx = tid & 31, ty = tid >> 5;
        for (int j = 0; j < 4; ++j)
            t[ty + 8 * j][tx] = W[(size_t)(k0 + ty + 8 * j) * 512 + n0 + tx];
        __syncthreads();
        for (int j = 0; j < 4; ++j)
            O[(size_t)(n0 + ty + 8 * j) * 512 + k0 + tx] = __float2bfloat16(t[tx][ty + 8 * j]);
    } else {
        int i = ((bid - 1024) * 256 + tid) * 4;   // covers exactly 8192*512
        float4 v = *reinterpret_cast<const float4*>(X + i);
        uint2 u;
        u.x = pkbf(v.x, v.y);
        u.y = pkbf(v.z, v.w);
        *reinterpret_cast<uint2*>(Xb + i) = u;
    }
}

// ---------------------------------------------------------------- fused QKV GEMM (R6)
__global__ __launch_bounds__(256, 2) void gemm_qkv(
    const __hip_bfloat16* __restrict__ A, const __hip_bfloat16* __restrict__ Bt,
    const float* __restrict__ bq, const float* __restrict__ bk, const float* __restrict__ bv,
    __hip_bfloat16* __restrict__ Qb, __hip_bfloat16* __restrict__ Kb,
    __hip_bfloat16* __restrict__ Vtb, float qs)
{
    const int K = 512;
    __shared__ __hip_bfloat16 Abuf[128 * 32];
    __shared__ __hip_bfloat16 Bbuf[128 * 32];
    const int tid = threadIdx.x, w = tid >> 6, lane = tid & 63;
    const int col = lane & 15, quad = lane >> 4;
    const int wr = w >> 1, wc = w & 1;
    const int tileN = blockIdx.x * 128, tileM = blockIdx.y * 128;

    f32x4 acc[4][4] = {};

    for (int k0 = 0; k0 < K; k0 += 32) {
        for (int i = 0; i < 2; ++i) {
            int g = w * 2 + i;
            int chunk = g * 64 + lane;
            int row = chunk >> 2, c8 = chunk & 3;
            gload16(A + (size_t)(tileM + row) * K + k0 + c8 * 8, Abuf + g * 512);
            gload16(Bt + (size_t)(tileN + row) * K + k0 + c8 * 8, Bbuf + g * 512);
        }
        __syncthreads();
        bf16x8 af[4], bfr[4];
        for (int mt = 0; mt < 4; ++mt)
            af[mt] = *reinterpret_cast<const bf16x8*>(Abuf + (wr * 64 + mt * 16 + col) * 32 + quad * 8);
        for (int nt = 0; nt < 4; ++nt)
            bfr[nt] = *reinterpret_cast<const bf16x8*>(Bbuf + (wc * 64 + nt * 16 + col) * 32 + quad * 8);
        for (int mt = 0; mt < 4; ++mt)
            for (int nt = 0; nt < 4; ++nt)
                acc[mt][nt] = mfma16(af[mt], bfr[nt], acc[mt][nt]);
        __syncthreads();
    }

    const int seg = (tileN + wc * 64) >> 9;   // wave-uniform
    const float* bias = (seg == 0) ? bq : (seg == 1) ? bk : bv;
    const float scale = (seg == 0) ? qs : 1.0f;
    __hip_bfloat16* outp = (seg == 0) ? Qb : (seg == 1) ? Kb : Vtb;

    for (int mt = 0; mt < 4; ++mt) {
        for (int nt = 0; nt < 4; ++nt) {
            int n = tileN + wc * 64 + nt * 16 + col;
            int nn = n & 511, h = nn >> 6, d = nn & 63;
            float bn = bias[nn];
            for (int r = 0; r < 4; ++r) {
                int m = tileM + wr * 64 + mt * 16 + quad * 4 + r;
                int b = m >> 12, s = m & 4095;
                float v = (acc[mt][nt][r] + bn) * scale;
                size_t off;
                if (seg < 2) off = (((size_t)(b * 8 + h) * 4096 + s) << 6) + d;
                else         off = (((size_t)(b * 8 + h) * 64 + d) << 12) + s;
                outp[off] = __float2bfloat16(v);
            }
        }
    }
}

// ---------------------------------------------------------------- final GEMM (Wo) (R6)
// 128(M) x 64(N) tiles -> 512 blocks = 2 blocks/CU.
__global__ __launch_bounds__(256, 2) void gemm_out(
    const __hip_bfloat16* __restrict__ A, const __hip_bfloat16* __restrict__ Bt,
    const float* __restrict__ bias, float* __restrict__ out)
{
    const int N = 512, K = 512;
    __shared__ __hip_bfloat16 Abuf[128 * 32];
    __shared__ __hip_bfloat16 Bbuf[64 * 32];
    const int tid = threadIdx.x, w = tid >> 6, lane = tid & 63;
    const int col = lane & 15, quad = lane >> 4;
    const int tileN = blockIdx.x * 64, tileM = blockIdx.y * 128;

    f32x4 acc[2][4] = {};

    for (int k0 = 0; k0 < K; k0 += 32) {
        for (int i = 0; i < 2; ++i) {
            int g = w * 2 + i;
            int chunk = g * 64 + lane;
            int row = chunk >> 2, c8 = chunk & 3;
            gload16(A + (size_t)(tileM + row) * K + k0 + c8 * 8, Abuf + g * 512);
        }
        {
            int row = tid >> 2, c8 = tid & 3;
            gload16(Bt + (size_t)(tileN + row) * K + k0 + c8 * 8, Bbuf + tid * 8);
        }
        __syncthreads();
        bf16x8 af[2], bfr[4];
        for (int mt = 0; mt < 2; ++mt)
            af[mt] = *reinterpret_cast<const bf16x8*>(Abuf + (w * 32 + mt * 16 + col) * 32 + quad * 8);
        for (int nt = 0; nt < 4; ++nt)
            bfr[nt] = *reinterpret_cast<const bf16x8*>(Bbuf + (nt * 16 + col) * 32 + quad * 8);
        for (int mt = 0; mt < 2; ++mt)
            for (int nt = 0; nt < 4; ++nt)
                acc[mt][nt] = mfma16(af[mt], bfr[nt], acc[mt][nt]);
        __syncthreads();
    }

    for (int mt = 0; mt < 2; ++mt) {
        for (int nt = 0; nt < 4; ++nt) {
            int n = tileN + nt * 16 + col;
            float bn = bias[n];
            for (int r = 0; r < 4; ++r) {
                int m = tileM + w * 32 + mt * 16 + quad * 4 + r;
                out[(size_t)m * N + n] = acc[mt][nt][r] + bn;
            }
        }
    }
}

// ---------------------------------------------------------------- flash attention (v8b)
// v4 skeleton, 32x32x16 MFMA, in-register softmax exchange.
// Per wave: 32 q-rows. lane&31 = q-column, lane>>5 = half h.
// QK (swapped): D[k][q], k32 = (reg&3)+8*(reg>>2)+4h per 32-k group.
// Pack exp(P) pairs -> U[m][t'] covering k = 32*(m>>2)+8*(m&3)+4h+{2t',2t'+1}.
// PV B-frag word w on half h needs U[2kb+h][w&1] from half w>>1: one
// permlane32_swap of (U[2kb][t'], U[2kb+1][t']) yields both output words.
// No LDS for P; LDS 32KB (KT 2x8K + VB 2x8K).
__global__ __launch_bounds__(256, 2) void flash(
    const __hip_bfloat16* __restrict__ Q,   // [B*H, 4096, 64] (pre-scaled)
    const __hip_bfloat16* __restrict__ Kq,  // [B*H, 4096, 64]
    const __hip_bfloat16* __restrict__ Vt,  // [B*H, 64, 4096]
    __hip_bfloat16* __restrict__ attnb)     // [B, 4096, 512]
{
    __shared__ __hip_bfloat16 KT[2][4096];  // 16 KB
    __shared__ __hip_bfloat16 VB[2][4096];  // 16 KB

    const int bh = blockIdx.y, b = bh >> 3, hq = bh & 7;
    const int tid = threadIdx.x, w = tid >> 6, lane = tid & 63;
    const int l31 = lane & 31, hh = lane >> 5, l7 = lane & 7;
    const int q0 = blockIdx.x * 128 + w * 32;

    const __hip_bfloat16* Qh = Q + (size_t)bh * 4096 * 64;
    const __hip_bfloat16* Kh = Kq + (size_t)bh * 4096 * 64;
    const __hip_bfloat16* Vh = Vt + (size_t)bh * 64 * 4096;

    // Q fragments (B-operand): lane q = l31, d = dk*16 + hh*8 + j
    bf16x8 aq[4];
#pragma unroll
    for (int dk = 0; dk < 4; ++dk)
        aq[dk] = *reinterpret_cast<const bf16x8*>(
            Qh + (size_t)(q0 + l31) * 64 + dk * 16 + hh * 8);

    // K/V staging: identical to v4 (pre-swizzled global source, linear LDS).
    const __hip_bfloat16* ksrc[2];
    const __hip_bfloat16* vsrc[2];
    int ldsoff[2];
#pragma unroll
    for (int i = 0; i < 2; ++i) {
        int c = i * 256 + tid;
        int row = c >> 3, s8 = (c & 7) ^ (row & 7);
        ksrc[i] = Kh + row * 64 + s8 * 8;
        vsrc[i] = Vh + (size_t)row * 4096 + s8 * 8;
        ldsoff[i] = (i * 256 + w * 64) * 8;
    }

    bf16x8 ones;
#pragma unroll
    for (int j = 0; j < 8; ++j) ones[j] = (__bf16)1.0f;

    const f32x16 z16 = {};
    f32x16 o[2] = {};        // D[d][q]: d = dg*32 + (reg&3)+8*(reg>>2)+4hh
    f32x16 lacc = {};        // row-sums (all 16 rows identical)
    f32x16 sc[2][2];         // [parity][kg32]

    gload16(ksrc[0], &KT[0][ldsoff[0]]);
    gload16(ksrc[1], &KT[0][ldsoff[1]]);
    gload16(vsrc[0], &VB[0][ldsoff[0]]);
    gload16(vsrc[1], &VB[0][ldsoff[1]]);
    gload16(ksrc[0] + 4096, &KT[1][ldsoff[0]]);
    gload16(ksrc[1] + 4096, &KT[1][ldsoff[1]]);
    __syncthreads();

#define QK_STEP(KR_, SP2_)                                                      \
    _Pragma("unroll")                                                           \
    for (int kg = 0; kg < 2; ++kg) {                                            \
        _Pragma("unroll")                                                       \
        for (int dk = 0; dk < 4; ++dk) {                                        \
            bf16x8 ak = *reinterpret_cast<const bf16x8*>(                       \
                &KT[KR_][(kg * 32 + l31) * 64 + (((dk * 2 + hh) ^ l7) << 3)]);  \
            sc[SP2_][kg] = (dk == 0) ? mfma32(ak, aq[0], z16)                   \
                                     : mfma32(ak, aq[dk], sc[SP2_][kg]);        \
        }                                                                       \
    }

#define SOFTMAX_EXCHANGE(SP_)                                                   \
    uint32_t U[8][2];                                                           \
    _Pragma("unroll")                                                           \
    for (int kg = 0; kg < 2; ++kg) {                                            \
        f32x16 v = sc[SP_][kg];                                                 \
        _Pragma("unroll")                                                       \
        for (int rr = 0; rr < 4; ++rr) {                                        \
            U[kg * 4 + rr][0] = pkbf(__builtin_amdgcn_exp2f(v[rr * 4 + 0]),     \
                                     __builtin_amdgcn_exp2f(v[rr * 4 + 1]));    \
            U[kg * 4 + rr][1] = pkbf(__builtin_amdgcn_exp2f(v[rr * 4 + 2]),     \
                                     __builtin_amdgcn_exp2f(v[rr * 4 + 3]));    \
        }                                                                       \
    }                                                                           \
    bf16x8 bp[4];                                                               \
    _Pragma("unroll")                                                           \
    for (int kb = 0; kb < 4; ++kb) {                                            \
        _Pragma("unroll")                                                       \
        for (int t2 = 0; t2 < 2; ++t2)                                          \
            pl32swap(U[2 * kb][t2], U[2 * kb + 1][t2]);                         \
        union { uint32_t u[4]; bf16x8 v8; } cc;                                 \
        cc.u[0] = U[2 * kb][0];     cc.u[1] = U[2 * kb][1];                     \
        cc.u[2] = U[2 * kb + 1][0]; cc.u[3] = U[2 * kb + 1][1];                 \
        bp[kb] = cc.v8;                                                         \
    }

#define PV_STEP(VR_)                                                            \
    _Pragma("unroll")                                                           \
    for (int dg = 0; dg < 2; ++dg) {                                            \
        _Pragma("unroll")                                                       \
        for (int kb = 0; kb < 4; ++kb) {                                        \
            bf16x8 av = *reinterpret_cast<const bf16x8*>(                       \
                &VB[VR_][(dg * 32 + l31) * 64 + (((kb * 2 + hh) ^ l7) << 3)]);  \
            o[dg] = mfma32(av, bp[kb], o[dg]);                                  \
        }                                                                       \
    }                                                                           \
    _Pragma("unroll")                                                           \
    for (int kb = 0; kb < 4; ++kb) lacc = mfma32(ones, bp[kb], lacc);

    // prologue: scores for tile 0
    QK_STEP(0, 0)
    __syncthreads();

#define FLASH_BODY(T_, P_)                                                      \
    {                                                                           \
        const int kt_ = (T_);                                                   \
        int kk = kt_ + 2; if (kk > 63) kk = 63;                                 \
        gload16(ksrc[0] + (size_t)kk * 4096, &KT[(P_)][ldsoff[0]]);             \
        gload16(ksrc[1] + (size_t)kk * 4096, &KT[(P_)][ldsoff[1]]);             \
        gload16(vsrc[0] + (size_t)(kt_ + 1) * 64, &VB[1 - (P_)][ldsoff[0]]);    \
        gload16(vsrc[1] + (size_t)(kt_ + 1) * 64, &VB[1 - (P_)][ldsoff[1]]);    \
        SOFTMAX_EXCHANGE(P_)                                                    \
        QK_STEP(1 - (P_), 1 - (P_))                                             \
        PV_STEP(P_)                                                             \
        __syncthreads();                                                        \
    }

    FLASH_BODY(0, 0)
    for (int kth = 0; kth < 31; ++kth) {
        FLASH_BODY(2 * kth + 1, 1)
        FLASH_BODY(2 * kth + 2, 0)
    }
    // tail: tile 63 — softmax sc[1], PV from VB[1]
    {
        SOFTMAX_EXCHANGE(1)
        PV_STEP(1)
    }
#undef FLASH_BODY
#undef PV_STEP
#undef SOFTMAX_EXCHANGE
#undef QK_STEP

    {
        float inv = 1.0f / lacc[0];
        int s = q0 + l31;
        __hip_bfloat16* dst = attnb + ((size_t)b * 4096 + s) * 512 + hq * 64;
#pragma unroll
        for (int dg = 0; dg < 2; ++dg)
#pragma unroll
            for (int rr = 0; rr < 4; ++rr) {
                uint2 u;
                u.x = pkbf(o[dg][rr * 4 + 0] * inv, o[dg][rr * 4 + 1] * inv);
                u.y = pkbf(o[dg][rr * 4 + 2] * inv, o[dg][rr * 4 + 3] * inv);
                *reinterpret_cast<uint2*>(dst + dg * 32 + rr * 8 + hh * 4) = u;
            }
    }
}

// ---------------------------------------------------------------- launch
extern "C" void kernel_launch(void* const* d_in, const int* in_sizes, int n_in,
                              void* d_out, int out_size, void* d_ws, size_t ws_size,
                              hipStream_t stream) {
    const float* X  = (const float*)d_in[0];
    const float* Wq = (const float*)d_in[1];
    const float* bq = (const float*)d_in[2];
    const float* Wk = (const float*)d_in[3];
    const float* bk = (const float*)d_in[4];
    const float* Wv = (const float*)d_in[5];
    const float* bv = (const float*)d_in[6];
    const float* Wo = (const float*)d_in[7];
    const float* bo = (const float*)d_in[8];
    float* out = (float*)d_out;

    char* ws = (char*)d_ws;
    __hip_bfloat16* Xb  = (__hip_bfloat16*)(ws);
    __hip_bfloat16* Wqt = (__hip_bfloat16*)(ws + ((size_t)8 << 20));
    __hip_bfloat16* Wkt = Wqt + 512 * 512;
    __hip_bfloat16* Wvt = Wkt + 512 * 512;
    __hip_bfloat16* Wot = Wvt + 512 * 512;
    __hip_bfloat16* Qb  = (__hip_bfloat16*)(ws + ((size_t)10 << 20));
    __hip_bfloat16* Kb  = (__hip_bfloat16*)(ws + ((size_t)18 << 20));
    __hip_bfloat16* Vtb = (__hip_bfloat16*)(ws + ((size_t)26 << 20));
    __hip_bfloat16* Atb = (__hip_bfloat16*)(ws + ((size_t)34 << 20));

    cvt_all<<<5120, 256, 0, stream>>>(X, Xb, Wq, Wk, Wv, Wo, Wqt, Wkt, Wvt, Wot);

    const float qs = 0.125f * 1.4426950408889634f;  // (1/sqrt(64)) * log2(e)
    gemm_qkv<<<dim3(12, 64), 256, 0, stream>>>(Xb, Wqt, bq, bk, bv, Qb, Kb, Vtb, qs);
    flash<<<dim3(32, 16), 256, 0, stream>>>(Qb, Kb, Vtb, Atb);
    gemm_out<<<dim3(8, 64), 256, 0, stream>>>(Atb, Wot, bo, out);
}